// Round 17
// baseline (426.525 us; speedup 1.0000x reference)
//
#include <hip/hip_runtime.h>
#include <stdint.h>

typedef __attribute__((ext_vector_type(8))) short short8;
typedef __attribute__((ext_vector_type(4))) float float4v;

#define SEQ 4096
#define HD 64
#define QB 128
#define KT 64
#define HEADS 16
#define NT (SEQ / KT)
#define MWORDS (SEQ / 64)       // uint64 mask words per row
#define TILE_BYTES 8192         // 64x64 bf16, fragment-order layout
#define QSCALE 0.18033688f      // 0.125 * log2(e)  (temperature + exp2 folding)

__device__ __forceinline__ ushort f2bf(float f) {
    union { float f; uint32_t u; } x; x.f = f;
    uint32_t u = x.u;
    return (ushort)((u + 0x7FFFu + ((u >> 16) & 1u)) >> 16);  // RNE
}

__device__ __forceinline__ uint32_t cvt_pk_bf16(float lo, float hi) {
    uint32_t r;
    asm("v_cvt_pk_bf16_f32 %0, %1, %2" : "=v"(r) : "v"(lo), "v"(hi));
    return r;
}

__device__ __forceinline__ float exp2_hw(float x) { return __builtin_amdgcn_exp2f(x); }
__device__ __forceinline__ float log2_hw(float x) { return __builtin_amdgcn_logf(x); }

__device__ __forceinline__ void gload_lds16(const void* g, void* l) {
    __builtin_amdgcn_global_load_lds(
        (const __attribute__((address_space(1))) uint32_t*)g,
        (__attribute__((address_space(3))) uint32_t*)l, 16, 0, 0);
}

// ---------------- mask bit-pack: [4096][4096] int32 -> [4096][64] uint64 ----------------
__global__ __launch_bounds__(256) void pack_mask_kernel(const int* __restrict__ mask,
                                                        unsigned long long* __restrict__ mb) {
    const int qrow = blockIdx.x;
    const int wave = threadIdx.x >> 6;
    const int lane = threadIdx.x & 63;
    const int* rp = mask + (size_t)qrow * SEQ;
    #pragma unroll
    for (int i = 0; i < 16; ++i) {
        const int widx = wave * 16 + i;
        const int mv = rp[widx * 64 + lane];
        unsigned long long b = __ballot(mv != 0);
        if (lane == 0) mb[(size_t)qrow * MWORDS + widx] = b;
    }
}

// ---------------- K/V -> bf16 tiles in MFMA fragment order ----------------
// K tile chunk ci = t*2+h, lane = g*16+li, 16B per lane:
//   K[kv(t,li)][h*32+g*8+e],  kv(t,m) = 32*(t>>1) + 8*(m>>2) + 4*(t&1) + (m&3)
// V tile chunk ci = dt*2+h:  V[h*32+g*8+e][dt*16+li]   (V^T fragment)
__global__ __launch_bounds__(256) void prep_kv_kernel(const float* __restrict__ kg,
                                                      const float* __restrict__ vg,
                                                      char* __restrict__ ktiles,
                                                      char* __restrict__ vtiles) {
    __shared__ __align__(16) float Tl[64][68];
    const int bid = blockIdx.x;               // head*64 + kt
    const int tid = threadIdx.x;
    const float* Kg = kg + (size_t)bid * KT * HD;
    const float* Vg = vg + (size_t)bid * KT * HD;
    char* Kt = ktiles + (size_t)bid * TILE_BYTES;
    char* Vt = vtiles + (size_t)bid * TILE_BYTES;

    {   // stage K coalesced
        const int r = tid >> 2, c0 = (tid & 3) * 16;
        #pragma unroll
        for (int j = 0; j < 4; ++j)
            *(float4v*)&Tl[r][c0 + j * 4] = *(const float4v*)(Kg + r * HD + c0 + j * 4);
    }
    __syncthreads();
    #pragma unroll
    for (int cc = 0; cc < 2; ++cc) {
        const int c = tid + cc * 256;
        const int t = c >> 7, h = (c >> 6) & 1, g = (c >> 4) & 3, li = c & 15;
        const int row = 32 * (t >> 1) + 8 * (li >> 2) + 4 * (t & 1) + (li & 3);
        const float* src = &Tl[row][h * 32 + g * 8];
        short8 w;
        #pragma unroll
        for (int e = 0; e < 8; ++e) w[e] = (short)f2bf(src[e]);
        *(short8*)(Kt + c * 16) = w;
    }
    __syncthreads();
    {   // stage V coalesced
        const int r = tid >> 2, c0 = (tid & 3) * 16;
        #pragma unroll
        for (int j = 0; j < 4; ++j)
            *(float4v*)&Tl[r][c0 + j * 4] = *(const float4v*)(Vg + r * HD + c0 + j * 4);
    }
    __syncthreads();
    #pragma unroll
    for (int cc = 0; cc < 2; ++cc) {
        const int c = tid + cc * 256;
        const int dt = c >> 7, h = (c >> 6) & 1, g = (c >> 4) & 3, li = c & 15;
        short8 w;
        #pragma unroll
        for (int e = 0; e < 8; ++e) w[e] = (short)f2bf(Tl[h * 32 + g * 8 + e][dt * 16 + li]);
        *(short8*)(Vt + c * 16) = w;
    }
}

// ---------------- lsum kernel: linv2[head][qrow] = -log2( sum_kv mask*exp2(s) ) --------
// 4 waves x 32 q-rows each (2 sets share every K fragment read) -> half the LDS
// reads and staging per q-row vs the monolithic pass 1; 4 blocks/CU (24 KB LDS).
__global__ __launch_bounds__(256, 4) void lsum_kernel(
    const float* __restrict__ qg, const unsigned long long* __restrict__ mb,
    const char* __restrict__ ktiles, float* __restrict__ lbuf)
{
    __shared__ __align__(16) char Lds3[3][TILE_BYTES];

    const int tid  = threadIdx.x;
    const int wave = tid >> 6;    // 0..3
    const int lane = tid & 63;
    const int g    = lane >> 4;
    const int li   = lane & 15;

    const int bid = blockIdx.x;               // 0..511
    const int blk = (bid & 7) * 64 + (bid >> 3);
    const int bh  = blk >> 5;
    const int qb  = blk & 31;

    const size_t qkvBase = (size_t)bh * SEQ * HD;
    const float* Qg = qg + qkvBase + (size_t)qb * QB * HD;
    const char* Ktile = ktiles + (size_t)bh * NT * TILE_BYTES;

    // ---- Q B-fragments for 2 q-sets (rows wave*32 + u*16 + li) ----
    short8 aq[2][2];
    #pragma unroll
    for (int u = 0; u < 2; ++u)
        #pragma unroll
        for (int h = 0; h < 2; ++h) {
            const float* src = Qg + (wave * 32 + u * 16 + li) * HD + h * 32 + g * 8;
            short8 t;
            #pragma unroll
            for (int e = 0; e < 8; ++e) t[e] = (short)f2bf(src[e] * QSCALE);
            aq[u][h] = t;
        }

    const int qrow0 = qb * QB + wave * 32 + li;
    const int qrow1 = qrow0 + 16;
    const unsigned long long* mrow0 = mb + (size_t)qrow0 * MWORDS;
    const unsigned long long* mrow1 = mb + (size_t)qrow1 * MWORDS;

#define STAGE_L(KTI, DST) do {                                                      \
    const char* _s = Ktile + (size_t)(KTI) * TILE_BYTES + wave * 2048 + lane * 16;  \
    char* _d = (char*)(DST) + wave * 2048;                                          \
    gload_lds16(_s, _d); gload_lds16(_s + 1024, _d + 1024);                         \
} while (0)

    STAGE_L(0, Lds3[0]);
    STAGE_L(1, Lds3[1]);
    asm volatile("s_waitcnt vmcnt(2)" ::: "memory");   // tile 0 landed; tile 1 in flight
    __builtin_amdgcn_s_barrier();
    asm volatile("" ::: "memory");

    float lsum[2] = {0.f, 0.f};
    for (int kt = 0; kt < NT; ++kt) {
        if (kt + 2 < NT) STAGE_L(kt + 2, Lds3[(kt + 2) % 3]);
        const unsigned long long mw0 = mrow0[kt];
        const unsigned long long mw1 = mrow1[kt];

        const char* Kb = Lds3[kt % 3] + lane * 16;
        short8 bk[4][2];
        #pragma unroll
        for (int t = 0; t < 4; ++t)
            #pragma unroll
            for (int h = 0; h < 2; ++h)
                bk[t][h] = *(const short8*)(Kb + (t * 2 + h) * 1024);

        #pragma unroll
        for (int u = 0; u < 2; ++u) {
            const unsigned long long mw = (u == 0) ? mw0 : mw1;
            float4v accs[4];
            #pragma unroll
            for (int t = 0; t < 4; ++t) accs[t] = (float4v){0.f, 0.f, 0.f, 0.f};
            __builtin_amdgcn_s_setprio(1);
            #pragma unroll
            for (int t = 0; t < 4; ++t) {
                accs[t] = __builtin_amdgcn_mfma_f32_16x16x32_bf16(bk[t][0], aq[u][0], accs[t], 0, 0, 0);
                accs[t] = __builtin_amdgcn_mfma_f32_16x16x32_bf16(bk[t][1], aq[u][1], accs[t], 0, 0, 0);
            }
            __builtin_amdgcn_s_setprio(0);
            const uint32_t mlo = (uint32_t)mw >> (g * 8);
            const uint32_t mhi = (uint32_t)(mw >> 32) >> (g * 8);
            const uint32_t nib[4] = { mlo & 0xFu, (mlo >> 4) & 0xFu, mhi & 0xFu, (mhi >> 4) & 0xFu };
            float ls = 0.f;
            #pragma unroll
            for (int t = 0; t < 4; ++t)
                #pragma unroll
                for (int r = 0; r < 4; ++r) {
                    const float e = exp2_hw(accs[t][r]);
                    ls += ((nib[t] >> r) & 1u) ? e : 0.f;
                }
            lsum[u] += ls;
        }
        if (kt < NT - 1) {
            // leave the 2 stage loads of tile kt+2 in flight; tile kt+1 (older) drained
            asm volatile("s_waitcnt vmcnt(2)" ::: "memory");
            __builtin_amdgcn_s_barrier();
            asm volatile("" ::: "memory");
        }
    }

    float* lb = lbuf + ((size_t)bh << 12);
    #pragma unroll
    for (int u = 0; u < 2; ++u) {
        float s = lsum[u];
        s += __shfl_xor(s, 16);
        s += __shfl_xor(s, 32);
        if (g == 0) lb[(u == 0) ? qrow0 : qrow1] = -log2_hw(s);
    }
#undef STAGE_L
}

// 8 waves: each wave stages 1KB of the 8KB tile with ONE gload_lds16
#define STAGE_K(KTI, DST) do {                                                     \
    const char* _s = Ktile + (size_t)(KTI) * TILE_BYTES + wave * 1024 + lane * 16; \
    gload_lds16(_s, (char*)(DST) + wave * 1024);                                   \
} while (0)

#define STAGE_V(KTI, DST) do {                                                     \
    const char* _s = Vtile + (size_t)(KTI) * TILE_BYTES + wave * 1024 + lane * 16; \
    gload_lds16(_s, (char*)(DST) + wave * 1024);                                   \
} while (0)

// ---------------- fused attention (pass 2 only): 8 waves, QB=128 ----------------
// linv2 comes precomputed from lsum_kernel. Same vmcnt discipline as R14:
//   barrier vmcnt(4): leaves exactly the 4 attn stores; stages+mask (older) drained.
__global__ __launch_bounds__(512, 4) void attn_kernel(
    const float* __restrict__ qg, const unsigned long long* __restrict__ mb,
    const char* __restrict__ ktiles, const char* __restrict__ vtiles,
    const float* __restrict__ lbuf,
    float* __restrict__ outg, float* __restrict__ attng)
{
    __shared__ __align__(16) char Lds[4][TILE_BYTES];   // K x2 + V x2

    const int tid  = threadIdx.x;
    const int wave = tid >> 6;    // 0..7
    const int lane = tid & 63;
    const int g    = lane >> 4;
    const int li   = lane & 15;

    // XCD-aware swizzle: 64 blocks (2 heads) per XCD -> K/V tiles L2-resident
    const int bid = blockIdx.x;               // 0..511
    const int blk = (bid & 7) * 64 + (bid >> 3);
    const int bh  = blk >> 5;
    const int qb  = blk & 31;

    const size_t qkvBase = (size_t)bh * SEQ * HD;
    const float* Qg = qg + qkvBase + (size_t)qb * QB * HD;
    const char* Ktile = ktiles + (size_t)bh * NT * TILE_BYTES;
    const char* Vtile = vtiles + (size_t)bh * NT * TILE_BYTES;

    // ---- Q B-fragments (0.125 * log2e folded) ----
    const int wq0 = wave * 16;
    short8 aq[2];
    #pragma unroll
    for (int h = 0; h < 2; ++h) {
        const float* src = Qg + (wq0 + li) * HD + h * 32 + g * 8;
        short8 t;
        #pragma unroll
        for (int e = 0; e < 8; ++e) t[e] = (short)f2bf(src[e] * QSCALE);
        aq[h] = t;
    }

    const int qrow = qb * QB + wq0 + li;          // this lane's q row (within head)
    const unsigned long long* mrow = mb + (size_t)qrow * MWORDS;
    const float linv2 = lbuf[((size_t)bh << 12) + qrow];   // log2(1/l), precomputed

    float* attnT = attng + (size_t)bh * SEQ * SEQ + (size_t)qrow * SEQ + g * 8;
    float4v acco[4];
    #pragma unroll
    for (int dt = 0; dt < 4; ++dt) acco[dt] = (float4v){0.f, 0.f, 0.f, 0.f};

    STAGE_K(0, Lds[0]);
    STAGE_V(0, Lds[2]);
    asm volatile("s_waitcnt vmcnt(0)" ::: "memory");
    __builtin_amdgcn_s_barrier();
    asm volatile("" ::: "memory");

    for (int kt = 0; kt < NT; ++kt) {
        const int b = kt & 1;
        if (kt < NT - 1) { STAGE_K(kt + 1, Lds[b ^ 1]); STAGE_V(kt + 1, Lds[2 + (b ^ 1)]); }
        const unsigned long long mw = mrow[kt];
        __builtin_amdgcn_sched_barrier(0);   // pin stage+mask issues above everything below

        const uint32_t mlo = (uint32_t)mw >> (g * 8);
        const uint32_t mhi = (uint32_t)(mw >> 32) >> (g * 8);

        const char* Kb = Lds[b] + lane * 16;
        const char* Vb = Lds[2 + b] + lane * 16;
        short8 bk[4][2], vb[4][2];
        #pragma unroll
        for (int t = 0; t < 4; ++t)
            #pragma unroll
            for (int h = 0; h < 2; ++h) {
                bk[t][h] = *(const short8*)(Kb + (t * 2 + h) * 1024);
                vb[t][h] = *(const short8*)(Vb + (t * 2 + h) * 1024);
            }

        float4v accs[4];
        #pragma unroll
        for (int t = 0; t < 4; ++t) accs[t] = (float4v){0.f, 0.f, 0.f, 0.f};
        __builtin_amdgcn_s_setprio(1);
        #pragma unroll
        for (int t = 0; t < 4; ++t) {
            accs[t] = __builtin_amdgcn_mfma_f32_16x16x32_bf16(bk[t][0], aq[0], accs[t], 0, 0, 0);
            accs[t] = __builtin_amdgcn_mfma_f32_16x16x32_bf16(bk[t][1], aq[1], accs[t], 0, 0, 0);
        }
        __builtin_amdgcn_s_setprio(0);

        // normalized P, fully in registers: p = mask ? exp2(acc + log2(1/l)) : 0
        const uint32_t nib[4] = { mlo & 0xFu, (mlo >> 4) & 0xFu, mhi & 0xFu, (mhi >> 4) & 0xFu };
        float4v pv[4];
        #pragma unroll
        for (int t = 0; t < 4; ++t) {
            #pragma unroll
            for (int r = 0; r < 4; ++r) {
                const float e = exp2_hw(accs[t][r] + linv2);
                pv[t][r] = ((nib[t] >> r) & 1u) ? e : 0.f;
            }
        }

        // PV B-fragment = register rename of packed pv
        uint32_t pk[4][2];
        #pragma unroll
        for (int t = 0; t < 4; ++t) {
            pk[t][0] = cvt_pk_bf16(pv[t][0], pv[t][1]);
            pk[t][1] = cvt_pk_bf16(pv[t][2], pv[t][3]);
        }
        union { uint32_t u[4]; short8 s; } pa0, pa1;
        pa0.u[0] = pk[0][0]; pa0.u[1] = pk[0][1]; pa0.u[2] = pk[1][0]; pa0.u[3] = pk[1][1];
        pa1.u[0] = pk[2][0]; pa1.u[1] = pk[2][1]; pa1.u[2] = pk[3][0]; pa1.u[3] = pk[3][1];

        __builtin_amdgcn_s_setprio(1);
        #pragma unroll
        for (int dt = 0; dt < 4; ++dt) {
            acco[dt] = __builtin_amdgcn_mfma_f32_16x16x32_bf16(vb[dt][0], pa0.s, acco[dt], 0, 0, 0);
            acco[dt] = __builtin_amdgcn_mfma_f32_16x16x32_bf16(vb[dt][1], pa1.s, acco[dt], 0, 0, 0);
        }
        __builtin_amdgcn_s_setprio(0);

        // attn stores: newest VMEM ops of this iteration (data-dependent on mask+LDS)
        float* ap = attnT + kt * KT;
        *(float4v*)(ap)      = pv[0];
        *(float4v*)(ap + 4)  = pv[1];
        *(float4v*)(ap + 32) = pv[2];
        *(float4v*)(ap + 36) = pv[3];

        if (kt < NT - 1) {
            // leave exactly the 4 stores in flight; stages+mask (older) drained
            asm volatile("s_waitcnt vmcnt(4)" ::: "memory");
            __builtin_amdgcn_s_barrier();
            asm volatile("" ::: "memory");
        }
    }

    // ---- write output: lane (g,li) owns out[qrow][dt*16+g*4 .. +3] ----
    float* outW = outg + qkvBase + (size_t)qrow * HD + g * 4;
    #pragma unroll
    for (int dt = 0; dt < 4; ++dt) {
        *(float4v*)(outW + dt * 16) = acco[dt];
    }
}

extern "C" void kernel_launch(void* const* d_in, const int* in_sizes, int n_in,
                              void* d_out, int out_size, void* d_ws, size_t ws_size,
                              hipStream_t stream) {
    (void)in_sizes; (void)n_in; (void)out_size; (void)ws_size;
    const float* q = (const float*)d_in[0];
    const float* k = (const float*)d_in[1];
    const float* v = (const float*)d_in[2];
    const int* mask = (const int*)d_in[3];

    float* outp  = (float*)d_out;
    float* attnp = outp + (size_t)2 * 8 * SEQ * HD;

    // ws: [0,2MB) mask bits | [2MB,10MB) K tiles | [10MB,18MB) V tiles | [18MB,+256KB) linv2
    char* ws = (char*)d_ws;
    unsigned long long* mb = (unsigned long long*)ws;
    char* ktiles = ws + (size_t)2 * 1024 * 1024;
    char* vtiles = ws + (size_t)10 * 1024 * 1024;
    float* lbuf  = (float*)(ws + (size_t)18 * 1024 * 1024);

    pack_mask_kernel<<<SEQ, 256, 0, stream>>>(mask, mb);
    prep_kv_kernel<<<HEADS * NT, 256, 0, stream>>>(k, v, ktiles, vtiles);
    lsum_kernel<<<HEADS * (SEQ / QB), 256, 0, stream>>>(q, mb, ktiles, lbuf);
    attn_kernel<<<HEADS * (SEQ / QB), 512, 0, stream>>>(q, mb, ktiles, vtiles, lbuf, outp, attnp);
}

// Round 18
// 382.948 us; speedup vs baseline: 1.1138x; 1.1138x over previous
//
#include <hip/hip_runtime.h>
#include <stdint.h>

typedef __attribute__((ext_vector_type(8))) short short8;
typedef __attribute__((ext_vector_type(4))) float float4v;

#define SEQ 4096
#define HD 64
#define QB 128
#define KT 64
#define HEADS 16
#define NT (SEQ / KT)
#define MWORDS (SEQ / 64)       // uint64 mask words per row
#define TILE_BYTES 8192         // 64x64 bf16, fragment-order layout
#define QSCALE 0.18033688f      // 0.125 * log2(e)  (temperature + exp2 folding)

__device__ __forceinline__ ushort f2bf(float f) {
    union { float f; uint32_t u; } x; x.f = f;
    uint32_t u = x.u;
    return (ushort)((u + 0x7FFFu + ((u >> 16) & 1u)) >> 16);  // RNE
}

__device__ __forceinline__ uint32_t cvt_pk_bf16(float lo, float hi) {
    uint32_t r;
    asm("v_cvt_pk_bf16_f32 %0, %1, %2" : "=v"(r) : "v"(lo), "v"(hi));
    return r;
}

__device__ __forceinline__ float exp2_hw(float x) { return __builtin_amdgcn_exp2f(x); }
__device__ __forceinline__ float log2_hw(float x) { return __builtin_amdgcn_logf(x); }

__device__ __forceinline__ void gload_lds16(const void* g, void* l) {
    __builtin_amdgcn_global_load_lds(
        (const __attribute__((address_space(1))) uint32_t*)g,
        (__attribute__((address_space(3))) uint32_t*)l, 16, 0, 0);
}

// ---------------- mask bit-pack: [4096][4096] int32 -> [4096][64] uint64 ----------------
__global__ __launch_bounds__(256) void pack_mask_kernel(const int* __restrict__ mask,
                                                        unsigned long long* __restrict__ mb) {
    const int qrow = blockIdx.x;
    const int wave = threadIdx.x >> 6;
    const int lane = threadIdx.x & 63;
    const int* rp = mask + (size_t)qrow * SEQ;
    #pragma unroll
    for (int i = 0; i < 16; ++i) {
        const int widx = wave * 16 + i;
        const int mv = rp[widx * 64 + lane];
        unsigned long long b = __ballot(mv != 0);
        if (lane == 0) mb[(size_t)qrow * MWORDS + widx] = b;
    }
}

// ---------------- K/V -> bf16 tiles in MFMA fragment order ----------------
__global__ __launch_bounds__(256) void prep_kv_kernel(const float* __restrict__ kg,
                                                      const float* __restrict__ vg,
                                                      char* __restrict__ ktiles,
                                                      char* __restrict__ vtiles) {
    __shared__ __align__(16) float Tl[64][68];
    const int bid = blockIdx.x;               // head*64 + kt
    const int tid = threadIdx.x;
    const float* Kg = kg + (size_t)bid * KT * HD;
    const float* Vg = vg + (size_t)bid * KT * HD;
    char* Kt = ktiles + (size_t)bid * TILE_BYTES;
    char* Vt = vtiles + (size_t)bid * TILE_BYTES;

    {   // stage K coalesced
        const int r = tid >> 2, c0 = (tid & 3) * 16;
        #pragma unroll
        for (int j = 0; j < 4; ++j)
            *(float4v*)&Tl[r][c0 + j * 4] = *(const float4v*)(Kg + r * HD + c0 + j * 4);
    }
    __syncthreads();
    #pragma unroll
    for (int cc = 0; cc < 2; ++cc) {
        const int c = tid + cc * 256;
        const int t = c >> 7, h = (c >> 6) & 1, g = (c >> 4) & 3, li = c & 15;
        const int row = 32 * (t >> 1) + 8 * (li >> 2) + 4 * (t & 1) + (li & 3);
        const float* src = &Tl[row][h * 32 + g * 8];
        short8 w;
        #pragma unroll
        for (int e = 0; e < 8; ++e) w[e] = (short)f2bf(src[e]);
        *(short8*)(Kt + c * 16) = w;
    }
    __syncthreads();
    {   // stage V coalesced
        const int r = tid >> 2, c0 = (tid & 3) * 16;
        #pragma unroll
        for (int j = 0; j < 4; ++j)
            *(float4v*)&Tl[r][c0 + j * 4] = *(const float4v*)(Vg + r * HD + c0 + j * 4);
    }
    __syncthreads();
    #pragma unroll
    for (int cc = 0; cc < 2; ++cc) {
        const int c = tid + cc * 256;
        const int dt = c >> 7, h = (c >> 6) & 1, g = (c >> 4) & 3, li = c & 15;
        short8 w;
        #pragma unroll
        for (int e = 0; e < 8; ++e) w[e] = (short)f2bf(Tl[h * 32 + g * 8 + e][dt * 16 + li]);
        *(short8*)(Vt + c * 16) = w;
    }
}

// pass-1 staging: 8 waves, each stages 1KB of the 8KB tile
#define STAGE_K8(KTI, DST) do {                                                    \
    const char* _s = Ktile + (size_t)(KTI) * TILE_BYTES + wave * 1024 + lane * 16; \
    gload_lds16(_s, (char*)(DST) + wave * 1024);                                   \
} while (0)

// pass-2 staging: EVEN waves only (ew = wave>>1 in 0..3), 2KB per even wave
#define STAGE2_K(KTI) do {                                                              \
    const char* _s = Ktile + (size_t)(KTI) * TILE_BYTES + ew * 2048 + lane * 16;        \
    char* _d = (char*)LdsK[(KTI) & 3] + ew * 2048;                                      \
    gload_lds16(_s, _d); gload_lds16(_s + 1024, _d + 1024);                             \
} while (0)

#define STAGE2_V(KTI) do {                                                              \
    const char* _s = Vtile + (size_t)(KTI) * TILE_BYTES + ew * 2048 + lane * 16;        \
    char* _d = (char*)LdsV[(KTI) & 3] + ew * 2048;                                      \
    gload_lds16(_s, _d); gload_lds16(_s + 1024, _d + 1024);                             \
} while (0)

// ---------------- fused attention: 8 waves, QB=128, phase-staggered pass 2 ------------
// Pass 2: each tile = two barrier slots {QK, FIN}; even waves run one slot ahead of
// odd waves so LDS/MFMA (QK) and exp/store/PV (FIN) phases co-occupy every slot.
// Staging by even waves only; mask prefetched one tile ahead AFTER the stores;
// uniform vmcnt(5) before each barrier (audited: drains exactly stale stores/stage).
__global__ __launch_bounds__(512, 4) void attn_kernel(
    const float* __restrict__ qg, const unsigned long long* __restrict__ mb,
    const char* __restrict__ ktiles, const char* __restrict__ vtiles,
    float* __restrict__ outg, float* __restrict__ attng)
{
    __shared__ __align__(16) char LdsK[4][TILE_BYTES];
    __shared__ __align__(16) char LdsV[4][TILE_BYTES];

    const int tid  = threadIdx.x;
    const int wave = tid >> 6;    // 0..7
    const int lane = tid & 63;
    const int g    = lane >> 4;
    const int li   = lane & 15;

    // XCD-aware swizzle: 64 blocks (2 heads) per XCD -> K/V tiles L2-resident
    const int bid = blockIdx.x;               // 0..511
    const int blk = (bid & 7) * 64 + (bid >> 3);
    const int bh  = blk >> 5;
    const int qb  = blk & 31;

    const size_t qkvBase = (size_t)bh * SEQ * HD;
    const float* Qg = qg + qkvBase + (size_t)qb * QB * HD;
    const char* Ktile = ktiles + (size_t)bh * NT * TILE_BYTES;
    const char* Vtile = vtiles + (size_t)bh * NT * TILE_BYTES;

    // ---- Q B-fragments (0.125 * log2e folded) ----
    const int wq0 = wave * 16;
    short8 aq[2];
    #pragma unroll
    for (int h = 0; h < 2; ++h) {
        const float* src = Qg + (wq0 + li) * HD + h * 32 + g * 8;
        short8 t;
        #pragma unroll
        for (int e = 0; e < 8; ++e) t[e] = (short)f2bf(src[e] * QSCALE);
        aq[h] = t;
    }

    const int qrow = qb * QB + wq0 + li;          // this lane's q row (within head)
    const unsigned long long* mrow = mb + (size_t)qrow * MWORDS;

    // ================= pass 1: row sums (R14-proven, 3-buffer, counted vmcnt) ==========
    STAGE_K8(0, LdsK[0]);
    STAGE_K8(1, LdsK[1]);
    asm volatile("s_waitcnt vmcnt(1)" ::: "memory");
    __builtin_amdgcn_s_barrier();
    asm volatile("" ::: "memory");

    float lsum = 0.f;
    for (int kt = 0; kt < NT; ++kt) {
        if (kt + 2 < NT) STAGE_K8(kt + 2, LdsK[(kt + 2) % 3]);
        const unsigned long long mw = mrow[kt];
        const uint32_t mlo = (uint32_t)mw >> (g * 8);
        const uint32_t mhi = (uint32_t)(mw >> 32) >> (g * 8);

        const char* Kb = LdsK[kt % 3] + lane * 16;
        short8 bk[4][2];
        #pragma unroll
        for (int t = 0; t < 4; ++t)
            #pragma unroll
            for (int h = 0; h < 2; ++h)
                bk[t][h] = *(const short8*)(Kb + (t * 2 + h) * 1024);

        float4v accs[4];
        #pragma unroll
        for (int t = 0; t < 4; ++t) accs[t] = (float4v){0.f, 0.f, 0.f, 0.f};
        __builtin_amdgcn_s_setprio(1);
        #pragma unroll
        for (int t = 0; t < 4; ++t) {
            accs[t] = __builtin_amdgcn_mfma_f32_16x16x32_bf16(bk[t][0], aq[0], accs[t], 0, 0, 0);
            accs[t] = __builtin_amdgcn_mfma_f32_16x16x32_bf16(bk[t][1], aq[1], accs[t], 0, 0, 0);
        }
        __builtin_amdgcn_s_setprio(0);
        const uint32_t nib[4] = { mlo & 0xFu, (mlo >> 4) & 0xFu, mhi & 0xFu, (mhi >> 4) & 0xFu };
        #pragma unroll
        for (int t = 0; t < 4; ++t) {
            #pragma unroll
            for (int r = 0; r < 4; ++r) {
                const float e = exp2_hw(accs[t][r]);
                lsum += ((nib[t] >> r) & 1u) ? e : 0.f;
            }
        }
        if (kt < NT - 2) {
            asm volatile("s_waitcnt vmcnt(2)" ::: "memory");
            __builtin_amdgcn_s_barrier();
            asm volatile("" ::: "memory");
        } else if (kt == NT - 2) {
            asm volatile("s_waitcnt vmcnt(1)" ::: "memory");
            __builtin_amdgcn_s_barrier();
            asm volatile("" ::: "memory");
        }
    }
    lsum += __shfl_xor(lsum, 16);
    lsum += __shfl_xor(lsum, 32);
    const float linv2 = -log2_hw(lsum);   // log2(1/l)

    // ================= pass 2: phase-staggered QK/FIN slots =================
    float* attnT = attng + (size_t)bh * SEQ * SEQ + (size_t)qrow * SEQ + g * 8;
    float4v acco[4];
    #pragma unroll
    for (int dt = 0; dt < 4; ++dt) acco[dt] = (float4v){0.f, 0.f, 0.f, 0.f};

    const int odd = wave & 1;
    const int ew  = wave >> 1;    // even-wave staging index (0..3 for waves 0,2,4,6)

    __syncthreads();              // pass-1 readers done before re-staging LdsK
    unsigned long long mwreg = mrow[0];
    if (!odd) {
        STAGE2_K(0); STAGE2_V(0);
        STAGE2_K(1); STAGE2_V(1);
        asm volatile("s_waitcnt vmcnt(0)" ::: "memory");
    }
    __builtin_amdgcn_s_barrier();
    asm volatile("" ::: "memory");

    float4v accs[4];
    for (int slot = 0; slot < 2 * NT + 1; ++slot) {
        const int half = slot & 1;
        int t_qk = -1, t_fin = -1;
        if (!odd) {
            if (!half) { const int t = slot >> 1; if (t < NT) t_qk = t; }
            else       t_fin = slot >> 1;
        } else {
            if (half)  t_qk = slot >> 1;
            else if (slot > 0) t_fin = (slot >> 1) - 1;
        }

        if (t_qk >= 0) {   // QK phase: stage (evens) + ds_read K + MFMA -> accs
            if (!odd && t_qk + 2 < NT) { STAGE2_K(t_qk + 2); STAGE2_V(t_qk + 2); }
            const char* Kb = LdsK[t_qk & 3] + lane * 16;
            short8 bk[4][2];
            #pragma unroll
            for (int t = 0; t < 4; ++t)
                #pragma unroll
                for (int h = 0; h < 2; ++h)
                    bk[t][h] = *(const short8*)(Kb + (t * 2 + h) * 1024);
            #pragma unroll
            for (int t = 0; t < 4; ++t) accs[t] = (float4v){0.f, 0.f, 0.f, 0.f};
            __builtin_amdgcn_s_setprio(1);
            #pragma unroll
            for (int t = 0; t < 4; ++t) {
                accs[t] = __builtin_amdgcn_mfma_f32_16x16x32_bf16(bk[t][0], aq[0], accs[t], 0, 0, 0);
                accs[t] = __builtin_amdgcn_mfma_f32_16x16x32_bf16(bk[t][1], aq[1], accs[t], 0, 0, 0);
            }
            __builtin_amdgcn_s_setprio(0);
        }

        if (t_fin >= 0) {  // FIN phase: ds_read V + softmax + stores + PV
            const char* Vb = LdsV[t_fin & 3] + lane * 16;
            short8 vb[4][2];
            #pragma unroll
            for (int t = 0; t < 4; ++t)
                #pragma unroll
                for (int h = 0; h < 2; ++h)
                    vb[t][h] = *(const short8*)(Vb + (t * 2 + h) * 1024);

            const uint32_t mlo = (uint32_t)mwreg >> (g * 8);
            const uint32_t mhi = (uint32_t)(mwreg >> 32) >> (g * 8);
            const uint32_t nib[4] = { mlo & 0xFu, (mlo >> 4) & 0xFu, mhi & 0xFu, (mhi >> 4) & 0xFu };
            float4v pv[4];
            #pragma unroll
            for (int t = 0; t < 4; ++t)
                #pragma unroll
                for (int r = 0; r < 4; ++r) {
                    const float e = exp2_hw(accs[t][r] + linv2);
                    pv[t][r] = ((nib[t] >> r) & 1u) ? e : 0.f;
                }

            // attn stores for tile t_fin
            float* ap = attnT + t_fin * KT;
            *(float4v*)(ap)      = pv[0];
            *(float4v*)(ap + 4)  = pv[1];
            *(float4v*)(ap + 32) = pv[2];
            *(float4v*)(ap + 36) = pv[3];

            // mask prefetch for next tile (AFTER stores: its use-wait 2 slots later
            // drains only older ops, never fresh stage loads)
            if (t_fin + 1 < NT) mwreg = mrow[t_fin + 1];

            uint32_t pk[4][2];
            #pragma unroll
            for (int t = 0; t < 4; ++t) {
                pk[t][0] = cvt_pk_bf16(pv[t][0], pv[t][1]);
                pk[t][1] = cvt_pk_bf16(pv[t][2], pv[t][3]);
            }
            union { uint32_t u[4]; short8 s; } pa0, pa1;
            pa0.u[0] = pk[0][0]; pa0.u[1] = pk[0][1]; pa0.u[2] = pk[1][0]; pa0.u[3] = pk[1][1];
            pa1.u[0] = pk[2][0]; pa1.u[1] = pk[2][1]; pa1.u[2] = pk[3][0]; pa1.u[3] = pk[3][1];

            __builtin_amdgcn_s_setprio(1);
            #pragma unroll
            for (int dt = 0; dt < 4; ++dt) {
                acco[dt] = __builtin_amdgcn_mfma_f32_16x16x32_bf16(vb[dt][0], pa0.s, acco[dt], 0, 0, 0);
                acco[dt] = __builtin_amdgcn_mfma_f32_16x16x32_bf16(vb[dt][1], pa1.s, acco[dt], 0, 0, 0);
            }
            __builtin_amdgcn_s_setprio(0);
        }

        if (slot < 2 * NT) {
            if (t_qk >= 0 || t_fin >= 0)
                asm volatile("s_waitcnt vmcnt(5)" ::: "memory");
            __builtin_amdgcn_s_barrier();
            asm volatile("" ::: "memory");
        }
    }

    // ---- write output: lane (g,li) owns out[qrow][dt*16+g*4 .. +3] ----
    float* outW = outg + qkvBase + (size_t)qrow * HD + g * 4;
    #pragma unroll
    for (int dt = 0; dt < 4; ++dt) {
        *(float4v*)(outW + dt * 16) = acco[dt];
    }
}

extern "C" void kernel_launch(void* const* d_in, const int* in_sizes, int n_in,
                              void* d_out, int out_size, void* d_ws, size_t ws_size,
                              hipStream_t stream) {
    (void)in_sizes; (void)n_in; (void)out_size; (void)ws_size;
    const float* q = (const float*)d_in[0];
    const float* k = (const float*)d_in[1];
    const float* v = (const float*)d_in[2];
    const int* mask = (const int*)d_in[3];

    float* outp  = (float*)d_out;
    float* attnp = outp + (size_t)2 * 8 * SEQ * HD;

    // ws layout: [0,2MB) mask bits | [2MB,10MB) K tiles | [10MB,18MB) V tiles
    char* ws = (char*)d_ws;
    unsigned long long* mb = (unsigned long long*)ws;
    char* ktiles = ws + (size_t)2 * 1024 * 1024;
    char* vtiles = ws + (size_t)10 * 1024 * 1024;

    pack_mask_kernel<<<SEQ, 256, 0, stream>>>(mask, mb);
    prep_kv_kernel<<<HEADS * NT, 256, 0, stream>>>(k, v, ktiles, vtiles);
    attn_kernel<<<HEADS * (SEQ / QB), 512, 0, stream>>>(q, mb, ktiles, vtiles, outp, attnp);
}